// Round 22
// baseline (61.807 us; speedup 1.0000x reference)
//
#include <hip/hip_runtime.h>

#define NB   8
#define ND   64
#define NP   1024
#define KDIM 128
#define HID  256
#define OUTD 256
#define CSC  2.885390081777927f   // 2*log2(e)
#define PSTR2 264                 // sred plane stride (mod 32 = 8)

typedef __attribute__((ext_vector_type(8))) short  bf16x8;
typedef __attribute__((ext_vector_type(4))) float  f32x4;

// E-trick: sigma = rcp(fma(Ed,Ep,1)); tanh = 1-2*sigma. EhpT transposed.
// R22: UN-FUSE. R16-R21: fused kernel stuck ~40us at 1 block/CU (barriers
// idle the whole CU; compiler sinks prefetch). S/A2 round-trip costs only
// ~0.5us of L2. Three 256-thread streaming kernels (8 blocks/CU, 32 waves)
// keep comb4 (1 rcp per 4 sigma), 2-row i-pairing, coalesced EhpT/Efp.

__device__ __forceinline__ ushort f2bf(float f) {
    unsigned u = __float_as_uint(f);
    return (ushort)((u + 0x7FFFu + ((u >> 16) & 1u)) >> 16);
}

// sum_{i=1..4} c_i/u_i added to acc, one rcp (exact algebra).
__device__ __forceinline__ float comb4(float u1, float u2, float u3, float u4,
                                       float c1, float c2, float c3, float c4,
                                       float acc) {
    float p12 = u1 * u2, p34 = u3 * u4;
    float P   = p12 * p34;
    float t1  = fmaf(c1, u2, c2 * u1);
    float t2  = fmaf(c3, u4, c4 * u3);
    float num = fmaf(t1, p34, t2 * p12);
    return fmaf(num, __builtin_amdgcn_rcpf(P), acc);
}

// K0: cast X -> bf16 (k-contig); W -> bf16 TRANSPOSED (WT[n][k]).
__global__ __launch_bounds__(256) void k_cast(
    const float* __restrict__ Xd, const float* __restrict__ Xp,
    const float* __restrict__ Wd, const float* __restrict__ Wa,
    const float* __restrict__ Wp, const float* __restrict__ Wb,
    ushort* __restrict__ Xdbf, ushort* __restrict__ Xpbf,
    ushort* __restrict__ WdT, ushort* __restrict__ WaT,
    ushort* __restrict__ WpT, ushort* __restrict__ WbT) {
    int blk = blockIdx.x, t = threadIdx.x;
    if (blk < 1024) {
        size_t i = ((size_t)blk << 10) + ((size_t)t << 2);
        float4 v = *(const float4*)(Xp + i);
        ushort4 o; o.x = f2bf(v.x); o.y = f2bf(v.y); o.z = f2bf(v.z); o.w = f2bf(v.w);
        *(ushort4*)(Xpbf + i) = o;
    } else if (blk < 1088) {
        size_t i = ((size_t)(blk - 1024) << 10) + ((size_t)t << 2);
        float4 v = *(const float4*)(Xd + i);
        ushort4 o; o.x = f2bf(v.x); o.y = f2bf(v.y); o.z = f2bf(v.z); o.w = f2bf(v.w);
        *(ushort4*)(Xdbf + i) = o;
    } else {
        int r = blk - 1088, mat = r >> 5;
        const float* W = (mat == 0) ? Wd : (mat == 1) ? Wa : (mat == 2) ? Wp : Wb;
        ushort* WT = (mat == 0) ? WdT : (mat == 1) ? WaT : (mat == 2) ? WpT : WbT;
        int o0 = ((r & 31) << 10) + (t << 2);
        int n = o0 >> 7, k0 = o0 & 127;
        ushort4 o;
        o.x = f2bf(W[(k0 + 0) * HID + n]);
        o.y = f2bf(W[(k0 + 1) * HID + n]);
        o.z = f2bf(W[(k0 + 2) * HID + n]);
        o.w = f2bf(W[(k0 + 3) * HID + n]);
        *(ushort4*)(WT + o0) = o;
    }
}

// K1: MFMA projection + fused exp2 (verified absmax 0.0625).
__global__ __launch_bounds__(256) void k_proj_mfma(
    const ushort* __restrict__ Xpbf, const ushort* __restrict__ Xdbf,
    const ushort* __restrict__ WdT, const ushort* __restrict__ WaT,
    const ushort* __restrict__ WpT, const ushort* __restrict__ WbT,
    float* __restrict__ Ehd, float* __restrict__ Efd,
    float* __restrict__ EhpT, float* __restrict__ Efp) {
    int blk = blockIdx.x, t = threadIdx.x;
    const ushort *A, *B;
    float* out; size_t obase; int ostride, am0, bn0;
    if (blk < 512) {
        int mt = blk >> 2, nt = blk & 3;
        A = Xpbf; am0 = mt * 64; B = WbT; bn0 = nt * 64;
        out = Efp; obase = (size_t)am0 * HID + bn0; ostride = HID;
    } else if (blk < 1024) {
        int r = blk - 512, b = r >> 6, rr = r & 63;
        int mt = rr >> 4, nt = rr & 15;
        A = WpT; am0 = mt * 64;
        B = Xpbf + (size_t)b * NP * KDIM; bn0 = nt * 64;
        out = EhpT; obase = ((size_t)(b * 256 + am0)) * NP + bn0; ostride = NP;
    } else if (blk < 1056) {
        int r = blk - 1024; int mt = r >> 2, nt = r & 3;
        A = Xdbf; am0 = mt * 64; B = WdT; bn0 = nt * 64;
        out = Ehd; obase = (size_t)am0 * HID + bn0; ostride = HID;
    } else {
        int r = blk - 1056; int mt = r >> 2, nt = r & 3;
        A = Xdbf; am0 = mt * 64; B = WaT; bn0 = nt * 64;
        out = Efd; obase = (size_t)am0 * HID + bn0; ostride = HID;
    }
    int l = t & 63, w = t >> 6;
    int wm = (w >> 1) << 5, wn = (w & 1) << 5;
    int lr = l & 15, lk = (l >> 4) << 3;
    const ushort* Ab = A + (size_t)(am0 + wm + lr) * KDIM + lk;
    const ushort* Bb = B + (size_t)(bn0 + wn + lr) * KDIM + lk;

    bf16x8 af[2][4], bfr[2][4];
#pragma unroll
    for (int f = 0; f < 2; ++f)
#pragma unroll
        for (int ks = 0; ks < 4; ++ks) {
            af[f][ks]  = *(const bf16x8*)(Ab + (size_t)(f << 4) * KDIM + (ks << 5));
            bfr[f][ks] = *(const bf16x8*)(Bb + (size_t)(f << 4) * KDIM + (ks << 5));
        }

    f32x4 acc[2][2];
#pragma unroll
    for (int mf = 0; mf < 2; ++mf)
#pragma unroll
        for (int nf = 0; nf < 2; ++nf) acc[mf][nf] = (f32x4){0.f, 0.f, 0.f, 0.f};
#pragma unroll
    for (int ks = 0; ks < 4; ++ks)
#pragma unroll
        for (int mf = 0; mf < 2; ++mf)
#pragma unroll
            for (int nf = 0; nf < 2; ++nf)
                acc[mf][nf] = __builtin_amdgcn_mfma_f32_16x16x32_bf16(
                    af[mf][ks], bfr[nf][ks], acc[mf][nf], 0, 0, 0);

#pragma unroll
    for (int mf = 0; mf < 2; ++mf)
#pragma unroll
        for (int nf = 0; nf < 2; ++nf)
#pragma unroll
            for (int r = 0; r < 4; ++r) {
                int m = wm + (mf << 4) + ((l >> 4) << 2) + r;
                int n = wn + (nf << 4) + (l & 15);
                out[obase + (size_t)m * ostride + n] =
                    __builtin_amdgcn_exp2f(acc[mf][nf][r] * CSC);
            }
}

// K2: scores. Block = 2 i-rows x 256-j quarter; grid 1024, 256 thr (8 blk/CU).
// Thread: jq=t&63 (4 j), hq=t>>6 (64 h). comb4 over 4-h groups.
__global__ __launch_bounds__(256) void k_scores2(
    const float* __restrict__ Ehd, const float* __restrict__ EhpT,
    const float* __restrict__ wsc, float* __restrict__ S) {
    int blk = blockIdx.x;
    int b = blk & 7, pair = (blk >> 3) & 31, jh = blk >> 8;
    int row0 = b * ND + pair * 2;
    int t = threadIdx.x;
    __shared__ float2 hrow[256];     // 2 KB
    __shared__ float  w2s[256];      // 1 KB
    __shared__ float  sred[8 * PSTR2];  // 8.25 KB
    hrow[t] = make_float2(Ehd[((size_t)row0 << 8) + t],
                          Ehd[((size_t)(row0 + 1) << 8) + t]);
    w2s[t] = -2.0f * wsc[t];
    __syncthreads();

    int jq = t & 63, hq = t >> 6;
    const float* pB = EhpT + ((size_t)((b << 8) + (hq << 6))) * NP
                    + (jh << 8) + (jq << 2);
    float a00 = 0, a01 = 0, a02 = 0, a03 = 0;
    float a10 = 0, a11 = 0, a12 = 0, a13 = 0;
    for (int hg = 0; hg < 16; ++hg) {
        const float* pr = pB + (size_t)(hg << 2) * NP;
        float4 p0 = *(const float4*)(pr);
        float4 p1 = *(const float4*)(pr + NP);
        float4 p2 = *(const float4*)(pr + 2 * (size_t)NP);
        float4 p3 = *(const float4*)(pr + 3 * (size_t)NP);
        int h = (hq << 6) + (hg << 2);
        float2 h0 = hrow[h],     h1 = hrow[h + 1];
        float2 h2 = hrow[h + 2], h3 = hrow[h + 3];
        float w0 = w2s[h],     w1 = w2s[h + 1];
        float w2 = w2s[h + 2], w3 = w2s[h + 3];
        a00 = comb4(fmaf(h0.x, p0.x, 1.f), fmaf(h1.x, p1.x, 1.f),
                    fmaf(h2.x, p2.x, 1.f), fmaf(h3.x, p3.x, 1.f),
                    w0, w1, w2, w3, a00);
        a01 = comb4(fmaf(h0.x, p0.y, 1.f), fmaf(h1.x, p1.y, 1.f),
                    fmaf(h2.x, p2.y, 1.f), fmaf(h3.x, p3.y, 1.f),
                    w0, w1, w2, w3, a01);
        a02 = comb4(fmaf(h0.x, p0.z, 1.f), fmaf(h1.x, p1.z, 1.f),
                    fmaf(h2.x, p2.z, 1.f), fmaf(h3.x, p3.z, 1.f),
                    w0, w1, w2, w3, a02);
        a03 = comb4(fmaf(h0.x, p0.w, 1.f), fmaf(h1.x, p1.w, 1.f),
                    fmaf(h2.x, p2.w, 1.f), fmaf(h3.x, p3.w, 1.f),
                    w0, w1, w2, w3, a03);
        a10 = comb4(fmaf(h0.y, p0.x, 1.f), fmaf(h1.y, p1.x, 1.f),
                    fmaf(h2.y, p2.x, 1.f), fmaf(h3.y, p3.x, 1.f),
                    w0, w1, w2, w3, a10);
        a11 = comb4(fmaf(h0.y, p0.y, 1.f), fmaf(h1.y, p1.y, 1.f),
                    fmaf(h2.y, p2.y, 1.f), fmaf(h3.y, p3.y, 1.f),
                    w0, w1, w2, w3, a11);
        a12 = comb4(fmaf(h0.y, p0.z, 1.f), fmaf(h1.y, p1.z, 1.f),
                    fmaf(h2.y, p2.z, 1.f), fmaf(h3.y, p3.z, 1.f),
                    w0, w1, w2, w3, a12);
        a13 = comb4(fmaf(h0.y, p0.w, 1.f), fmaf(h1.y, p1.w, 1.f),
                    fmaf(h2.y, p2.w, 1.f), fmaf(h3.y, p3.w, 1.f),
                    w0, w1, w2, w3, a13);
    }
    int base = (hq << 6) + jq;
    sred[0 * PSTR2 + base] = a00;  sred[1 * PSTR2 + base] = a01;
    sred[2 * PSTR2 + base] = a02;  sred[3 * PSTR2 + base] = a03;
    sred[4 * PSTR2 + base] = a10;  sred[5 * PSTR2 + base] = a11;
    sred[6 * PSTR2 + base] = a12;  sred[7 * PSTR2 + base] = a13;
    __syncthreads();

    // output j = t (within quarter): plane = (t&3), col = (t>>2); sum 4 hq.
    int c = t & 3, jq2 = t >> 2;
    const float* q0 = sred + c * PSTR2 + jq2;
    const float* q1 = sred + (4 + c) * PSTR2 + jq2;
    float s0 = (q0[0] + q0[64]) + (q0[128] + q0[192]);
    float s1 = (q1[0] + q1[64]) + (q1[128] + q1[192]);
    S[((size_t)row0 << 10) + (jh << 8) + t] = s0;
    S[((size_t)(row0 + 1) << 10) + (jh << 8) + t] = s1;
}

// K3: softmax over j per row, in place; writes A2 = -2*A.
// No max pass: |S| <= 2*sum|w| <= 32, exp2 arg <= ~46 -> fp32-safe.
__global__ __launch_bounds__(256) void k_softmax(float* __restrict__ S) {
    int row = blockIdx.x;
    int t = threadIdx.x;
    float* Srow = S + ((size_t)row << 10);
    float4 v = ((float4*)Srow)[t];
    const float L2E = 1.4426950408889634f;
    v.x = __builtin_amdgcn_exp2f(v.x * L2E);
    v.y = __builtin_amdgcn_exp2f(v.y * L2E);
    v.z = __builtin_amdgcn_exp2f(v.z * L2E);
    v.w = __builtin_amdgcn_exp2f(v.w * L2E);
    float s4 = (v.x + v.y) + (v.z + v.w);
#pragma unroll
    for (int off = 32; off > 0; off >>= 1) s4 += __shfl_xor(s4, off, 64);
    __shared__ float wsum[4];
    if ((t & 63) == 0) wsum[t >> 6] = s4;
    __syncthreads();
    float tot = (wsum[0] + wsum[1]) + (wsum[2] + wsum[3]);
    float sneg = -2.0f * __builtin_amdgcn_rcpf(tot);   // A2 = -2*A
    v.x *= sneg; v.y *= sneg; v.z *= sneg; v.w *= sneg;
    ((float4*)Srow)[t] = v;
}

// K4: facc. Block = 2 i-rows x 256-j quarter; grid 1024, 256 thr.
// Thread: oq=t&63 (4 o), jg=t>>6 (64 j). comb4 over 4-j groups.
// npart layout [row][jh][256].
__global__ __launch_bounds__(256) void k_facc2(
    const float* __restrict__ Efd, const float* __restrict__ Efp,
    const float* __restrict__ A2, float* __restrict__ npart) {
    int blk = blockIdx.x;
    int b = blk & 7, pair = (blk >> 3) & 31, jh = blk >> 8;
    int row0 = b * ND + pair * 2;
    int t = threadIdx.x;
    __shared__ float2 a2s[256];         // 2 KB
    __shared__ float  sred[8 * PSTR2];  // 8.25 KB
    a2s[t] = make_float2(A2[((size_t)row0 << 10) + (jh << 8) + t],
                         A2[((size_t)(row0 + 1) << 10) + (jh << 8) + t]);
    __syncthreads();

    int oq = t & 63, jg = t >> 6;
    int o0 = oq << 2;
    float4 fd0 = *(const float4*)(Efd + ((size_t)row0 << 8) + o0);
    float4 fd1 = *(const float4*)(Efd + ((size_t)(row0 + 1) << 8) + o0);
    const float* fpB = Efp + ((size_t)(b * NP + (jh << 8) + (jg << 6)) << 8) + o0;
    float b00 = 0, b01 = 0, b02 = 0, b03 = 0;
    float b10 = 0, b11 = 0, b12 = 0, b13 = 0;
    for (int g = 0; g < 16; ++g) {
        const float* fr = fpB + ((size_t)(g << 2) << 8);
        float4 f0 = *(const float4*)(fr);
        float4 f1 = *(const float4*)(fr + 256);
        float4 f2 = *(const float4*)(fr + 512);
        float4 f3 = *(const float4*)(fr + 768);
        int j0 = (jg << 6) + (g << 2);
        float2 A0 = a2s[j0],      A1 = a2s[j0 + 1];
        float2 A2v = a2s[j0 + 2], A3 = a2s[j0 + 3];
        b00 = comb4(fmaf(fd0.x, f0.x, 1.f), fmaf(fd0.x, f1.x, 1.f),
                    fmaf(fd0.x, f2.x, 1.f), fmaf(fd0.x, f3.x, 1.f),
                    A0.x, A1.x, A2v.x, A3.x, b00);
        b01 = comb4(fmaf(fd0.y, f0.y, 1.f), fmaf(fd0.y, f1.y, 1.f),
                    fmaf(fd0.y, f2.y, 1.f), fmaf(fd0.y, f3.y, 1.f),
                    A0.x, A1.x, A2v.x, A3.x, b01);
        b02 = comb4(fmaf(fd0.z, f0.z, 1.f), fmaf(fd0.z, f1.z, 1.f),
                    fmaf(fd0.z, f2.z, 1.f), fmaf(fd0.z, f3.z, 1.f),
                    A0.x, A1.x, A2v.x, A3.x, b02);
        b03 = comb4(fmaf(fd0.w, f0.w, 1.f), fmaf(fd0.w, f1.w, 1.f),
                    fmaf(fd0.w, f2.w, 1.f), fmaf(fd0.w, f3.w, 1.f),
                    A0.x, A1.x, A2v.x, A3.x, b03);
        b10 = comb4(fmaf(fd1.x, f0.x, 1.f), fmaf(fd1.x, f1.x, 1.f),
                    fmaf(fd1.x, f2.x, 1.f), fmaf(fd1.x, f3.x, 1.f),
                    A0.y, A1.y, A2v.y, A3.y, b10);
        b11 = comb4(fmaf(fd1.y, f0.y, 1.f), fmaf(fd1.y, f1.y, 1.f),
                    fmaf(fd1.y, f2.y, 1.f), fmaf(fd1.y, f3.y, 1.f),
                    A0.y, A1.y, A2v.y, A3.y, b11);
        b12 = comb4(fmaf(fd1.z, f0.z, 1.f), fmaf(fd1.z, f1.z, 1.f),
                    fmaf(fd1.z, f2.z, 1.f), fmaf(fd1.z, f3.z, 1.f),
                    A0.y, A1.y, A2v.y, A3.y, b12);
        b13 = comb4(fmaf(fd1.w, f0.w, 1.f), fmaf(fd1.w, f1.w, 1.f),
                    fmaf(fd1.w, f2.w, 1.f), fmaf(fd1.w, f3.w, 1.f),
                    A0.y, A1.y, A2v.y, A3.y, b13);
    }
    int base = (jg << 6) + oq;
    sred[0 * PSTR2 + base] = b00;  sred[1 * PSTR2 + base] = b01;
    sred[2 * PSTR2 + base] = b02;  sred[3 * PSTR2 + base] = b03;
    sred[4 * PSTR2 + base] = b10;  sred[5 * PSTR2 + base] = b11;
    sred[6 * PSTR2 + base] = b12;  sred[7 * PSTR2 + base] = b13;
    __syncthreads();

    // output o = t: plane = (t&3), col = (t>>2); sum 4 jg groups.
    int c = t & 3, oq2 = t >> 2;
    const float* q0 = sred + c * PSTR2 + oq2;
    const float* q1 = sred + (4 + c) * PSTR2 + oq2;
    float s0 = (q0[0] + q0[64]) + (q0[128] + q0[192]);
    float s1 = (q1[0] + q1[64]) + (q1[128] + q1[192]);
    npart[((((size_t)row0 << 2) + jh) << 8) + t] = s0;
    npart[((((size_t)(row0 + 1) << 2) + jh) << 8) + t] = s1;
}

// K5: out[b][o] = 64 + sum over 256 (i,jh) combos. grid = 64 (8b x 8 o-chunks).
__global__ __launch_bounds__(256) void k_reduce(
    const float* __restrict__ npart, float* __restrict__ out) {
    int b = blockIdx.x >> 3, oc = blockIdx.x & 7;
    int t = threadIdx.x;
    int o = oc * 32 + (t & 31), q0 = t >> 5;   // q0 = 0..7
    float s = 0.f;
#pragma unroll
    for (int k = 0; k < 32; ++k)
        s += npart[((size_t)(b * 256 + q0 + (k << 3)) << 8) + o];
    __shared__ float red[256];
    red[t] = s; __syncthreads();
    for (int st = 128; st >= 32; st >>= 1) {
        if (t < st) red[t] += red[t + st];
        __syncthreads();
    }
    if (t < 32) out[(b << 8) + oc * 32 + t] = 64.0f + red[t];
}

extern "C" void kernel_launch(void* const* d_in, const int* in_sizes, int n_in,
                              void* d_out, int out_size, void* d_ws, size_t ws_size,
                              hipStream_t stream) {
    const float* Xd  = (const float*)d_in[0];
    const float* Xp  = (const float*)d_in[1];
    const float* Wd  = (const float*)d_in[2];
    const float* Wp  = (const float*)d_in[3];
    const float* Wa  = (const float*)d_in[4];
    const float* Wb  = (const float*)d_in[5];
    const float* wsc = (const float*)d_in[6];
    float* out = (float*)d_out;

    float* ws = (float*)d_ws;
    float* Ehd  = ws;                         // 131072 f
    float* Efd  = Ehd + NB * ND * HID;        // 131072 f
    float* EhpT = Efd + NB * ND * OUTD;       // 2097152 f
    float* Efp  = EhpT + NB * NP * HID;       // 2097152 f
    float* stage = Efp + NB * NP * OUTD;      // bf16 staging region
    ushort* Xpbf = (ushort*)stage;
    ushort* Xdbf = Xpbf + NB * NP * KDIM;
    ushort* WdT  = Xdbf + 65536;
    ushort* WaT  = WdT + 32768;
    ushort* WpT  = WaT + 32768;
    ushort* WbT  = WpT + 32768;
    float* S     = stage;                     // 524288 f (overlays dead staging)
    float* npart = stage + 622592;            // 524288 f ([row][4][256])

    k_cast     <<<1216, 256, 0, stream>>>(Xd, Xp, Wd, Wa, Wp, Wb,
                                          Xdbf, Xpbf, WdT, WaT, WpT, WbT);
    k_proj_mfma<<<1088, 256, 0, stream>>>(Xpbf, Xdbf, WdT, WaT, WpT, WbT,
                                          Ehd, Efd, EhpT, Efp);
    k_scores2  <<<1024, 256, 0, stream>>>(Ehd, EhpT, wsc, S);
    k_softmax  <<<NB * ND, 256, 0, stream>>>(S);
    k_facc2    <<<1024, 256, 0, stream>>>(Efd, Efp, S, npart);
    k_reduce   <<<64, 256, 0, stream>>>(npart, out);
}

// Round 23
// 59.230 us; speedup vs baseline: 1.0435x; 1.0435x over previous
//
#include <hip/hip_runtime.h>

#define NB   8
#define ND   64
#define NP   1024
#define KDIM 128
#define HID  256
#define OUTD 256
#define CSC  2.885390081777927f   // 2*log2(e)
#define PSTR 1032                 // sred plane stride (mod 32 = 8)

typedef __attribute__((ext_vector_type(8))) short  bf16x8;
typedef __attribute__((ext_vector_type(4))) float  f32x4;

// E-trick: sigma = rcp(fma(Ed,Ep,1)); tanh = 1-2*sigma. EhpT transposed.
// R23 = R21 + R20: comb4 (1 rcp / 4 sigma, -25% issue floor, proven -3.6us)
// COMBINED with deferred normalization + j-halving -> grid 512, 2 blocks/CU
// (32 waves) so co-resident blocks hide the per-iteration LDS/VMEM waits
// that capped fused kernels at ~40us. hw4 packs (h0,h1,-2w) into one b128.

__device__ __forceinline__ ushort f2bf(float f) {
    unsigned u = __float_as_uint(f);
    return (ushort)((u + 0x7FFFu + ((u >> 16) & 1u)) >> 16);
}

// sum_{i=1..4} c_i/u_i added to acc, one rcp (exact algebra).
__device__ __forceinline__ float comb4(float u1, float u2, float u3, float u4,
                                       float c1, float c2, float c3, float c4,
                                       float acc) {
    float p12 = u1 * u2, p34 = u3 * u4;
    float P   = p12 * p34;
    float t1  = fmaf(c1, u2, c2 * u1);
    float t2  = fmaf(c3, u4, c4 * u3);
    float num = fmaf(t1, p34, t2 * p12);
    return fmaf(num, __builtin_amdgcn_rcpf(P), acc);
}

// K0: cast X -> bf16 (k-contig); W -> bf16 TRANSPOSED (WT[n][k]).
__global__ __launch_bounds__(256) void k_cast(
    const float* __restrict__ Xd, const float* __restrict__ Xp,
    const float* __restrict__ Wd, const float* __restrict__ Wa,
    const float* __restrict__ Wp, const float* __restrict__ Wb,
    ushort* __restrict__ Xdbf, ushort* __restrict__ Xpbf,
    ushort* __restrict__ WdT, ushort* __restrict__ WaT,
    ushort* __restrict__ WpT, ushort* __restrict__ WbT) {
    int blk = blockIdx.x, t = threadIdx.x;
    if (blk < 1024) {
        size_t i = ((size_t)blk << 10) + ((size_t)t << 2);
        float4 v = *(const float4*)(Xp + i);
        ushort4 o; o.x = f2bf(v.x); o.y = f2bf(v.y); o.z = f2bf(v.z); o.w = f2bf(v.w);
        *(ushort4*)(Xpbf + i) = o;
    } else if (blk < 1088) {
        size_t i = ((size_t)(blk - 1024) << 10) + ((size_t)t << 2);
        float4 v = *(const float4*)(Xd + i);
        ushort4 o; o.x = f2bf(v.x); o.y = f2bf(v.y); o.z = f2bf(v.z); o.w = f2bf(v.w);
        *(ushort4*)(Xdbf + i) = o;
    } else {
        int r = blk - 1088, mat = r >> 5;
        const float* W = (mat == 0) ? Wd : (mat == 1) ? Wa : (mat == 2) ? Wp : Wb;
        ushort* WT = (mat == 0) ? WdT : (mat == 1) ? WaT : (mat == 2) ? WpT : WbT;
        int o0 = ((r & 31) << 10) + (t << 2);
        int n = o0 >> 7, k0 = o0 & 127;
        ushort4 o;
        o.x = f2bf(W[(k0 + 0) * HID + n]);
        o.y = f2bf(W[(k0 + 1) * HID + n]);
        o.z = f2bf(W[(k0 + 2) * HID + n]);
        o.w = f2bf(W[(k0 + 3) * HID + n]);
        *(ushort4*)(WT + o0) = o;
    }
}

// K1: MFMA projection + fused exp2 (verified absmax 0.0625).
__global__ __launch_bounds__(256) void k_proj_mfma(
    const ushort* __restrict__ Xpbf, const ushort* __restrict__ Xdbf,
    const ushort* __restrict__ WdT, const ushort* __restrict__ WaT,
    const ushort* __restrict__ WpT, const ushort* __restrict__ WbT,
    float* __restrict__ Ehd, float* __restrict__ Efd,
    float* __restrict__ EhpT, float* __restrict__ Efp) {
    int blk = blockIdx.x, t = threadIdx.x;
    const ushort *A, *B;
    float* out; size_t obase; int ostride, am0, bn0;
    if (blk < 512) {
        int mt = blk >> 2, nt = blk & 3;
        A = Xpbf; am0 = mt * 64; B = WbT; bn0 = nt * 64;
        out = Efp; obase = (size_t)am0 * HID + bn0; ostride = HID;
    } else if (blk < 1024) {
        int r = blk - 512, b = r >> 6, rr = r & 63;
        int mt = rr >> 4, nt = rr & 15;
        A = WpT; am0 = mt * 64;
        B = Xpbf + (size_t)b * NP * KDIM; bn0 = nt * 64;
        out = EhpT; obase = ((size_t)(b * 256 + am0)) * NP + bn0; ostride = NP;
    } else if (blk < 1056) {
        int r = blk - 1024; int mt = r >> 2, nt = r & 3;
        A = Xdbf; am0 = mt * 64; B = WdT; bn0 = nt * 64;
        out = Ehd; obase = (size_t)am0 * HID + bn0; ostride = HID;
    } else {
        int r = blk - 1056; int mt = r >> 2, nt = r & 3;
        A = Xdbf; am0 = mt * 64; B = WaT; bn0 = nt * 64;
        out = Efd; obase = (size_t)am0 * HID + bn0; ostride = HID;
    }
    int l = t & 63, w = t >> 6;
    int wm = (w >> 1) << 5, wn = (w & 1) << 5;
    int lr = l & 15, lk = (l >> 4) << 3;
    const ushort* Ab = A + (size_t)(am0 + wm + lr) * KDIM + lk;
    const ushort* Bb = B + (size_t)(bn0 + wn + lr) * KDIM + lk;

    bf16x8 af[2][4], bfr[2][4];
#pragma unroll
    for (int f = 0; f < 2; ++f)
#pragma unroll
        for (int ks = 0; ks < 4; ++ks) {
            af[f][ks]  = *(const bf16x8*)(Ab + (size_t)(f << 4) * KDIM + (ks << 5));
            bfr[f][ks] = *(const bf16x8*)(Bb + (size_t)(f << 4) * KDIM + (ks << 5));
        }

    f32x4 acc[2][2];
#pragma unroll
    for (int mf = 0; mf < 2; ++mf)
#pragma unroll
        for (int nf = 0; nf < 2; ++nf) acc[mf][nf] = (f32x4){0.f, 0.f, 0.f, 0.f};
#pragma unroll
    for (int ks = 0; ks < 4; ++ks)
#pragma unroll
        for (int mf = 0; mf < 2; ++mf)
#pragma unroll
            for (int nf = 0; nf < 2; ++nf)
                acc[mf][nf] = __builtin_amdgcn_mfma_f32_16x16x32_bf16(
                    af[mf][ks], bfr[nf][ks], acc[mf][nf], 0, 0, 0);

#pragma unroll
    for (int mf = 0; mf < 2; ++mf)
#pragma unroll
        for (int nf = 0; nf < 2; ++nf)
#pragma unroll
            for (int r = 0; r < 4; ++r) {
                int m = wm + (mf << 4) + ((l >> 4) << 2) + r;
                int n = wn + (nf << 4) + (l & 15);
                out[obase + (size_t)m * ostride + n] =
                    __builtin_amdgcn_exp2f(acc[mf][nf][r] * CSC);
            }
}

// K2: FUSED scores+exp+facc (deferred norm). 2 i-rows x 512-j half per
// block; grid 512 (b=blk&7, pair=(blk>>3)&31, jh=blk>>8), 1024 threads,
// 2 blocks/CU. comb4 everywhere; hw4 = (Ehd_r0, Ehd_r1, -2w) b128.
__global__ __launch_bounds__(1024, 8) void k_fused(
    const float* __restrict__ Ehd, const float* __restrict__ EhpT,
    const float* __restrict__ Efd, const float* __restrict__ Efp,
    const float* __restrict__ wsc, float* __restrict__ num,
    float* __restrict__ den) {
    int blk = blockIdx.x;
    int b = blk & 7, pair = (blk >> 3) & 31, jh = blk >> 8;
    int row0 = b * ND + pair * 2;
    int t = threadIdx.x;

    __shared__ float4 hw4[256];          // 4 KB
    __shared__ float2 a2[512];           // 4 KB  (-2u r0, -2u r1)
    __shared__ float  sred[8 * PSTR];    // 33 KB
    __shared__ float  wsum0[8], wsum1[8];

    if (t < 256)
        hw4[t] = make_float4(Ehd[((size_t)row0 << 8) + t],
                             Ehd[((size_t)(row0 + 1) << 8) + t],
                             -2.0f * wsc[t], 0.f);
    __syncthreads();

    // ---- phase 1: shifted scores over 512 j x 256 h ----
    {
        int jq = t & 127, hq = t >> 7;       // 4 j each; hq 0..7 (32 h each)
        const float* pB = EhpT + ((size_t)((b << 8) + (hq << 5))) * NP
                        + (jh << 9) + (jq << 2);
        float a00 = 0, a01 = 0, a02 = 0, a03 = 0;
        float a10 = 0, a11 = 0, a12 = 0, a13 = 0;
        for (int hg = 0; hg < 8; ++hg) {
            const float* pr = pB + (size_t)(hg << 2) * NP;
            float4 p0 = *(const float4*)(pr);
            float4 p1 = *(const float4*)(pr + NP);
            float4 p2 = *(const float4*)(pr + 2 * (size_t)NP);
            float4 p3 = *(const float4*)(pr + 3 * (size_t)NP);
            int h = (hq << 5) + (hg << 2);
            float4 hw0 = hw4[h],     hw1 = hw4[h + 1];
            float4 hw2 = hw4[h + 2], hw3 = hw4[h + 3];
            a00 = comb4(fmaf(hw0.x, p0.x, 1.f), fmaf(hw1.x, p1.x, 1.f),
                        fmaf(hw2.x, p2.x, 1.f), fmaf(hw3.x, p3.x, 1.f),
                        hw0.z, hw1.z, hw2.z, hw3.z, a00);
            a01 = comb4(fmaf(hw0.x, p0.y, 1.f), fmaf(hw1.x, p1.y, 1.f),
                        fmaf(hw2.x, p2.y, 1.f), fmaf(hw3.x, p3.y, 1.f),
                        hw0.z, hw1.z, hw2.z, hw3.z, a01);
            a02 = comb4(fmaf(hw0.x, p0.z, 1.f), fmaf(hw1.x, p1.z, 1.f),
                        fmaf(hw2.x, p2.z, 1.f), fmaf(hw3.x, p3.z, 1.f),
                        hw0.z, hw1.z, hw2.z, hw3.z, a02);
            a03 = comb4(fmaf(hw0.x, p0.w, 1.f), fmaf(hw1.x, p1.w, 1.f),
                        fmaf(hw2.x, p2.w, 1.f), fmaf(hw3.x, p3.w, 1.f),
                        hw0.z, hw1.z, hw2.z, hw3.z, a03);
            a10 = comb4(fmaf(hw0.y, p0.x, 1.f), fmaf(hw1.y, p1.x, 1.f),
                        fmaf(hw2.y, p2.x, 1.f), fmaf(hw3.y, p3.x, 1.f),
                        hw0.z, hw1.z, hw2.z, hw3.z, a10);
            a11 = comb4(fmaf(hw0.y, p0.y, 1.f), fmaf(hw1.y, p1.y, 1.f),
                        fmaf(hw2.y, p2.y, 1.f), fmaf(hw3.y, p3.y, 1.f),
                        hw0.z, hw1.z, hw2.z, hw3.z, a11);
            a12 = comb4(fmaf(hw0.y, p0.z, 1.f), fmaf(hw1.y, p1.z, 1.f),
                        fmaf(hw2.y, p2.z, 1.f), fmaf(hw3.y, p3.z, 1.f),
                        hw0.z, hw1.z, hw2.z, hw3.z, a12);
            a13 = comb4(fmaf(hw0.y, p0.w, 1.f), fmaf(hw1.y, p1.w, 1.f),
                        fmaf(hw2.y, p2.w, 1.f), fmaf(hw3.y, p3.w, 1.f),
                        hw0.z, hw1.z, hw2.z, hw3.z, a13);
        }
        int base = (hq << 7) + jq;
        sred[0 * PSTR + base] = a00;  sred[1 * PSTR + base] = a01;
        sred[2 * PSTR + base] = a02;  sred[3 * PSTR + base] = a03;
        sred[4 * PSTR + base] = a10;  sred[5 * PSTR + base] = a11;
        sred[6 * PSTR + base] = a12;  sred[7 * PSTR + base] = a13;
    }
    __syncthreads();

    // ---- phase 2: u = e^s (unnormalized), a2 = -2u, den partials ----
    if (t < 512) {
        int jq2 = t >> 2, c = t & 3;
        const float* p0 = sred + c * PSTR + jq2;
        const float* p1 = sred + (4 + c) * PSTR + jq2;
        float sc0 = 0.f, sc1 = 0.f;
#pragma unroll
        for (int hq = 0; hq < 8; ++hq) {
            sc0 += p0[hq << 7];
            sc1 += p1[hq << 7];
        }
        const float L2E = 1.4426950408889634f;
        float u0 = __builtin_amdgcn_exp2f(sc0 * L2E);
        float u1 = __builtin_amdgcn_exp2f(sc1 * L2E);
        a2[t] = make_float2(-2.f * u0, -2.f * u1);
        float s0 = u0, s1 = u1;
#pragma unroll
        for (int off = 32; off > 0; off >>= 1) {
            s0 += __shfl_xor(s0, off, 64);
            s1 += __shfl_xor(s1, off, 64);
        }
        if ((t & 63) == 0) { wsum0[t >> 6] = s0; wsum1[t >> 6] = s1; }
    }
    __syncthreads();
    if (t == 0) {
        float d0 = 0.f, d1 = 0.f;
#pragma unroll
        for (int w = 0; w < 8; ++w) { d0 += wsum0[w]; d1 += wsum1[w]; }
        den[((size_t)row0 << 1) + jh] = d0;
        den[((size_t)(row0 + 1) << 1) + jh] = d1;
    }

    // ---- phase 3: num partials over 512 j x 256 o ----
    {
        int oq = t & 63, jg = t >> 6;        // 4 o each; jg 0..15 (32 j each)
        int o0 = oq << 2;
        float4 fd0 = *(const float4*)(Efd + ((size_t)row0 << 8) + o0);
        float4 fd1 = *(const float4*)(Efd + ((size_t)(row0 + 1) << 8) + o0);
        const float* fpB = Efp + ((size_t)(b * NP + (jh << 9) + (jg << 5)) << 8) + o0;
        float b00 = 0, b01 = 0, b02 = 0, b03 = 0;
        float b10 = 0, b11 = 0, b12 = 0, b13 = 0;
        for (int g = 0; g < 8; ++g) {
            const float* fr = fpB + ((size_t)(g << 2) << 8);
            float4 f0 = *(const float4*)(fr);
            float4 f1 = *(const float4*)(fr + 256);
            float4 f2 = *(const float4*)(fr + 512);
            float4 f3 = *(const float4*)(fr + 768);
            int j0 = (jg << 5) + (g << 2);
            float2 A0 = a2[j0],      A1 = a2[j0 + 1];
            float2 A2v = a2[j0 + 2], A3 = a2[j0 + 3];
            b00 = comb4(fmaf(fd0.x, f0.x, 1.f), fmaf(fd0.x, f1.x, 1.f),
                        fmaf(fd0.x, f2.x, 1.f), fmaf(fd0.x, f3.x, 1.f),
                        A0.x, A1.x, A2v.x, A3.x, b00);
            b01 = comb4(fmaf(fd0.y, f0.y, 1.f), fmaf(fd0.y, f1.y, 1.f),
                        fmaf(fd0.y, f2.y, 1.f), fmaf(fd0.y, f3.y, 1.f),
                        A0.x, A1.x, A2v.x, A3.x, b01);
            b02 = comb4(fmaf(fd0.z, f0.z, 1.f), fmaf(fd0.z, f1.z, 1.f),
                        fmaf(fd0.z, f2.z, 1.f), fmaf(fd0.z, f3.z, 1.f),
                        A0.x, A1.x, A2v.x, A3.x, b02);
            b03 = comb4(fmaf(fd0.w, f0.w, 1.f), fmaf(fd0.w, f1.w, 1.f),
                        fmaf(fd0.w, f2.w, 1.f), fmaf(fd0.w, f3.w, 1.f),
                        A0.x, A1.x, A2v.x, A3.x, b03);
            b10 = comb4(fmaf(fd1.x, f0.x, 1.f), fmaf(fd1.x, f1.x, 1.f),
                        fmaf(fd1.x, f2.x, 1.f), fmaf(fd1.x, f3.x, 1.f),
                        A0.y, A1.y, A2v.y, A3.y, b10);
            b11 = comb4(fmaf(fd1.y, f0.y, 1.f), fmaf(fd1.y, f1.y, 1.f),
                        fmaf(fd1.y, f2.y, 1.f), fmaf(fd1.y, f3.y, 1.f),
                        A0.y, A1.y, A2v.y, A3.y, b11);
            b12 = comb4(fmaf(fd1.z, f0.z, 1.f), fmaf(fd1.z, f1.z, 1.f),
                        fmaf(fd1.z, f2.z, 1.f), fmaf(fd1.z, f3.z, 1.f),
                        A0.y, A1.y, A2v.y, A3.y, b12);
            b13 = comb4(fmaf(fd1.w, f0.w, 1.f), fmaf(fd1.w, f1.w, 1.f),
                        fmaf(fd1.w, f2.w, 1.f), fmaf(fd1.w, f3.w, 1.f),
                        A0.y, A1.y, A2v.y, A3.y, b13);
        }
        __syncthreads();                 // phase-2 sred reads done
        int base = (jg << 6) + oq;
        sred[0 * PSTR + base] = b00;  sred[1 * PSTR + base] = b01;
        sred[2 * PSTR + base] = b02;  sred[3 * PSTR + base] = b03;
        sred[4 * PSTR + base] = b10;  sred[5 * PSTR + base] = b11;
        sred[6 * PSTR + base] = b12;  sred[7 * PSTR + base] = b13;
    }
    __syncthreads();

    if (t < 512) {
        int r = t >> 8, o = t & 255;
        int oq2 = o >> 2, c2 = o & 3;
        const float* pk = sred + ((r << 2) + c2) * PSTR + oq2;
        float s = 0.f;
#pragma unroll
        for (int g = 0; g < 16; ++g) s += pk[g << 6];
        num[((((size_t)(row0 + r) << 1) + jh) << 8) + o] = s;
    }
}

// K3: out[b][o] = 64 + sum_i (num0+num1) * rcp(den0+den1). grid = 8.
__global__ __launch_bounds__(256) void k_reduce(
    const float* __restrict__ num, const float* __restrict__ den,
    float* __restrict__ out) {
    int b = blockIdx.x, t = threadIdx.x;
    float s = 64.0f;
    for (int i = 0; i < 64; ++i) {
        size_t row = (size_t)(b * 64 + i);
        float D = den[row << 1] + den[(row << 1) + 1];
        const float* nb = num + ((row << 1) << 8) + t;
        float n = nb[0] + nb[256];
        s += n * __builtin_amdgcn_rcpf(D);
    }
    out[(b << 8) + t] = s;
}

extern "C" void kernel_launch(void* const* d_in, const int* in_sizes, int n_in,
                              void* d_out, int out_size, void* d_ws, size_t ws_size,
                              hipStream_t stream) {
    const float* Xd  = (const float*)d_in[0];
    const float* Xp  = (const float*)d_in[1];
    const float* Wd  = (const float*)d_in[2];
    const float* Wp  = (const float*)d_in[3];
    const float* Wa  = (const float*)d_in[4];
    const float* Wb  = (const float*)d_in[5];
    const float* wsc = (const float*)d_in[6];
    float* out = (float*)d_out;

    float* ws = (float*)d_ws;
    float* Ehd  = ws;                         // 131072 f
    float* Efd  = Ehd + NB * ND * HID;        // 131072 f
    float* EhpT = Efd + NB * ND * OUTD;       // 2097152 f
    float* Efp  = EhpT + NB * NP * HID;       // 2097152 f
    float* stage = Efp + NB * NP * OUTD;      // bf16 staging region
    ushort* Xpbf = (ushort*)stage;
    ushort* Xdbf = Xpbf + NB * NP * KDIM;
    ushort* WdT  = Xdbf + 65536;
    ushort* WaT  = WdT + 32768;
    ushort* WpT  = WaT + 32768;
    ushort* WbT  = WpT + 32768;
    float* numb = stage + 622592;             // 262144 f ([row][2][256])
    float* denb = numb + 262144;              // 1024 f   ([row][2])

    k_cast     <<<1216, 256, 0, stream>>>(Xd, Xp, Wd, Wa, Wp, Wb,
                                          Xdbf, Xpbf, WdT, WaT, WpT, WbT);
    k_proj_mfma<<<1088, 256, 0, stream>>>(Xpbf, Xdbf, WdT, WaT, WpT, WbT,
                                          Ehd, Efd, EhpT, Efp);
    k_fused    <<<512, 1024, 0, stream>>>(Ehd, EhpT, Efd, Efp, wsc, numb, denb);
    k_reduce   <<<NB, 256, 0, stream>>>(numb, denb, out);
}